// Round 5
// baseline (1181.258 us; speedup 1.0000x reference)
//
#include <hip/hip_runtime.h>

// ============================================================================
// CNN3_P r5:
//  - fc1: LDS-free barrier-free GEMM; M split 2x208 (wf1r padded to 416 rows),
//    block = 208m x 256n, all waves share A-frags (L1 dedup), panel-aware XCD
//    mapping keeps each slice's A-panel L2-resident. B-frags direct from
//    global (h3 / pre-converted bf16 x), both L3-resident.
//  - front: conv tiles MPW=8 (B-LDS-read feeds 8 MFMA -> LDS ops halved).
//  - chunkN=2048.
// ============================================================================

typedef __attribute__((ext_vector_type(8))) short bf16x8;
typedef __attribute__((ext_vector_type(4))) float f32x4;
typedef __attribute__((ext_vector_type(8))) unsigned short u16x8;
typedef __attribute__((ext_vector_type(4))) unsigned short u16x4;

#define DEVINL __device__ __forceinline__

DEVINL unsigned short f2bf(float f) {
  unsigned u = __builtin_bit_cast(unsigned, f);
  return (unsigned short)((u + 0x7fffu + ((u >> 16) & 1u)) >> 16);  // RNE
}
DEVINL float bf2f(unsigned short h) {
  return __builtin_bit_cast(float, ((unsigned)h) << 16);
}
DEVINL f32x4 mfma16(bf16x8 a, bf16x8 b, f32x4 c) {
  return __builtin_amdgcn_mfma_f32_16x16x32_bf16(a, b, c, 0, 0, 0);
}
DEVINL float relu(float v) { return v > 0.f ? v : 0.f; }
// swizzled LDS index (u16 units): row r, col c, row-stride 2^sh u16
DEVINL int sxg(int r, int c, int sh) {
  return (r << sh) + (((c >> 3) ^ (r & 7)) << 3) + (c & 7);
}

constexpr int NB = 4096;

// ---------------------------------------------------------------- prep weights
// wp1r: [p][i] 64x64. w1p/w2p/w3p per-fragment packed:
// frag f=(k*KS+ks)*MT+mt; lane l elem e: o=mt*16+(l&15), c=ks*32+(l>>4)*8+e
__global__ __launch_bounds__(256) void k_prep_w(
    const float* __restrict__ Wp, const float* __restrict__ W1,
    const float* __restrict__ W2, const float* __restrict__ W3,
    unsigned short* __restrict__ wp1r, unsigned short* __restrict__ w1p,
    unsigned short* __restrict__ w2p, unsigned short* __restrict__ w3p) {
  int idx = blockIdx.x * 256 + threadIdx.x;
  if (idx < 4096) {
    int p = idx >> 6, i = idx & 63;
    wp1r[idx] = f2bf(Wp[(p * 64 + i) * 2 + 1]);
    return;
  }
  idx -= 4096;
  if (idx < 24576) {  // w1: KS=2, MT=8
    int f = idx >> 9, l = (idx >> 3) & 63, e = idx & 7;
    int mt = f & 7, t = f >> 3, ks = t & 1, k = t >> 1;
    int o = mt * 16 + (l & 15), c = ks * 32 + (l >> 4) * 8 + e;
    w1p[idx] = f2bf(W1[(o * 64 + c) * 3 + k]);
    return;
  }
  idx -= 24576;
  if (idx < 98304) {  // w2: KS=4, MT=16
    int f = idx >> 9, l = (idx >> 3) & 63, e = idx & 7;
    int mt = f & 15, t = f >> 4, ks = t & 3, k = t >> 2;
    int o = mt * 16 + (l & 15), c = ks * 32 + (l >> 4) * 8 + e;
    w2p[idx] = f2bf(W2[(o * 128 + c) * 3 + k]);
    return;
  }
  idx -= 98304;
  if (idx < 196608) {  // w3: KS=8, MT=16
    int f = idx >> 9, l = (idx >> 3) & 63, e = idx & 7;
    int mt = f & 15, t = f >> 4, ks = t & 7, k = t >> 3;
    int o = mt * 16 + (l & 15), c = ks * 32 + (l >> 4) * 8 + e;
    w3p[idx] = f2bf(W3[(o * 256 + c) * 3 + k]);
  }
}

// ---------------------------------------------------------------- Wf1 remap
// rows 400..415 zero-padded (fc1 uses M=416)
__global__ __launch_bounds__(256) void k_prep_wf1(const float* __restrict__ wf1,
                                                  unsigned short* __restrict__ wf1r) {
  extern __shared__ unsigned short tls[];  // 256*130 u16
  const int m = blockIdx.x, tid = threadIdx.x;
  unsigned short* dst = wf1r + (size_t)m * 39168;
  if (m >= 400) {
    for (int idx = tid; idx < 39168; idx += 256) dst[idx] = 0;
    return;
  }
  const float* src = wf1 + (size_t)m * 39168;
  for (int idx = tid; idx < 30976; idx += 256) {
    int o = idx / 121, l = idx - o * 121;
    tls[o * 130 + l] = f2bf(src[idx]);
  }
  __syncthreads();
  for (int idx = tid; idx < 30976; idx += 256) {
    int l = idx >> 8, o = idx & 255;
    dst[idx] = tls[o * 130 + l];
  }
  __syncthreads();
  for (int idx = tid; idx < 8192; idx += 256) {
    int il = idx >> 7, cl = idx & 127;
    tls[cl * 66 + il] = f2bf(src[30976 + idx]);
  }
  __syncthreads();
  for (int idx = tid; idx < 8192; idx += 256) {
    int cl = idx >> 6, il = idx & 63;
    dst[30976 + idx] = tls[cl * 66 + il];
  }
}

// ---------------------------------------------------------------- conv phase
// wave-grid GM m-groups x GN n-groups; wave = MPW m-tiles x NPW n-tiles.
// A coalesced from packed global (1KB/frag, L1/L2), B swizzled LDS
// (each read feeds MPW MFMAs).
template <int CIN, int COUT, int LIN, int LOUT, int SSHI, int SSHO, int MPW,
          int NPW, bool TOGLB>
DEVINL void conv16(const unsigned short* in_lds,
                   const unsigned short* __restrict__ wpack,
                   const float* __restrict__ bias, unsigned short* out_lds,
                   unsigned short* h3, int b, int lane, int wv) {
  constexpr int KS = CIN / 32;
  constexpr int MT = COUT / 16;
  constexpr int GM = MT / MPW;
  constexpr int GN = 8 / GM;
  static_assert(GN * NPW == 8, "");
  const int lr = lane & 15, lq = lane >> 4;
  const int wm = wv / GN, wn = wv % GN;
  f32x4 acc[MPW][NPW];
#pragma unroll
  for (int mi = 0; mi < MPW; ++mi)
#pragma unroll
    for (int ni = 0; ni < NPW; ++ni) acc[mi][ni] = (f32x4){0.f, 0.f, 0.f, 0.f};
#pragma unroll
  for (int k = 0; k < 3; ++k)
#pragma unroll
    for (int ks = 0; ks < KS; ++ks) {
      bf16x8 a[MPW];
#pragma unroll
      for (int mi = 0; mi < MPW; ++mi)
        a[mi] = *(const bf16x8*)(wpack +
                                 (((k * KS + ks) * MT + wm * MPW + mi) << 9) +
                                 lane * 8);
      const int col = ks * 32 + lq * 8;
#pragma unroll
      for (int ni = 0; ni < NPW; ++ni) {
        int l = (wn * NPW + ni) * 16 + lr + k;
        if (l > LIN - 1) l = LIN - 1;  // garbage cols >= LOUT, never stored
        bf16x8 bb = *(const bf16x8*)(in_lds + sxg(l, col, SSHI));
#pragma unroll
        for (int mi = 0; mi < MPW; ++mi)
          acc[mi][ni] = mfma16(a[mi], bb, acc[mi][ni]);
      }
    }
#pragma unroll
  for (int mi = 0; mi < MPW; ++mi) {
    const int o0 = (wm * MPW + mi) * 16 + lq * 4;
    const f32x4 bi = *(const f32x4*)(bias + o0);
#pragma unroll
    for (int ni = 0; ni < NPW; ++ni) {
      const int l = (wn * NPW + ni) * 16 + lr;
      if (l < LOUT) {
        u16x4 pk;
#pragma unroll
        for (int r = 0; r < 4; ++r) pk[r] = f2bf(relu(acc[mi][ni][r] + bi[r]));
        if constexpr (TOGLB)
          *(u16x4*)(h3 + ((size_t)b * LOUT + l) * COUT + o0) = pk;
        else
          *(u16x4*)(out_lds + sxg(l, o0, SSHO)) = pk;
      }
    }
  }
}

// ---------------------------------------------------------------- fused front
// LDS regions (u16): A @0     : xs[128]<<6 -> h1s[125]<<7  (16000)
//                    B @16000 : h0s[127]<<6 -> h2s[123]<<8 (31488)
// dyn LDS = 94,976 B. Also writes x as bf16 (xbf) for fc1.
__global__ __launch_bounds__(512) void k_front(
    const float* __restrict__ x, const float* __restrict__ Wp,
    const float* __restrict__ bp, const unsigned short* __restrict__ wp1r,
    const unsigned short* __restrict__ w1p, const float* __restrict__ b1,
    const unsigned short* __restrict__ w2p, const float* __restrict__ b2,
    const unsigned short* __restrict__ w3p, const float* __restrict__ b3,
    unsigned short* __restrict__ h3, unsigned short* __restrict__ xbf) {
  extern __shared__ unsigned short lds[];
  unsigned short* xs = lds;
  unsigned short* h1s = lds;
  unsigned short* h0s = lds + 16000;
  unsigned short* h2s = lds + 16000;
  __shared__ float pbase[8][64];
  __shared__ float basel[64];
  const int b = blockIdx.x, tid = threadIdx.x;
  const int lane = tid & 63, wv = tid >> 6, lq = lane >> 4, lr = lane & 15;
  const float* xb = x + (size_t)b * 8192;

  // phase 0: stage x -> xs bf16 (swizzled) + write bf16 copy to global
  for (int idx = tid * 4; idx < 8192; idx += 2048) {
    f32x4 v = *(const f32x4*)(xb + idx);
    int c = idx >> 6, i = idx & 63;
    u16x4 pk;
#pragma unroll
    for (int r = 0; r < 4; ++r) pk[r] = f2bf(v[r]);
    *(u16x4*)(xs + sxg(c, i, 6)) = pk;
    *(u16x4*)(xbf + (size_t)b * 8192 + idx) = pk;
  }
  __syncthreads();

  // phase 0b: base[p] = sum_i Wp[p][i][0]*x[b][i]  (xs row 0 unswizzled)
  {
    int p = tid & 63, q = tid >> 6;
    float s = 0.f;
#pragma unroll
    for (int t = 0; t < 8; ++t) {
      int i = q * 8 + t;
      s += Wp[(p * 64 + i) * 2] * bf2f(xs[i]);
    }
    pbase[q][p] = s;
  }
  __syncthreads();
  if (tid < 64) {
    float s = bp[tid];
#pragma unroll
    for (int q = 0; q < 8; ++q) s += pbase[q][tid];
    basel[tid] = s;
  }
  __syncthreads();

  // phase 1: pairwise GEMM -> h0s[127][64]
  {
    const int mt = wv & 3, nh = wv >> 2;
    f32x4 acc[4];
#pragma unroll
    for (int t = 0; t < 4; ++t) acc[t] = (f32x4){0.f, 0.f, 0.f, 0.f};
#pragma unroll
    for (int s = 0; s < 2; ++s) {
      bf16x8 a = *(const bf16x8*)(wp1r + (mt * 16 + lr) * 64 + s * 32 + lq * 8);
#pragma unroll
      for (int t = 0; t < 4; ++t) {
        int j = (nh * 4 + t) * 16 + lr;
        int row = j + 1 > 127 ? 127 : j + 1;
        bf16x8 bb = *(const bf16x8*)(xs + sxg(row, s * 32 + lq * 8, 6));
        acc[t] = mfma16(a, bb, acc[t]);
      }
    }
    const int m0 = mt * 16 + lq * 4;
    f32x4 bl;
#pragma unroll
    for (int r = 0; r < 4; ++r) bl[r] = basel[m0 + r];
#pragma unroll
    for (int t = 0; t < 4; ++t) {
      int j = (nh * 4 + t) * 16 + lr;
      if (j < 127) {
        u16x4 pk;
#pragma unroll
        for (int r = 0; r < 4; ++r) pk[r] = f2bf(relu(acc[t][r] + bl[r]));
        *(u16x4*)(h0s + sxg(j, m0, 6)) = pk;
      }
    }
  }
  __syncthreads();

  // phase 2: conv1 64->128, 127->125 (wave = 8m x 1n)
  conv16<64, 128, 127, 125, 6, 7, 8, 1, false>(h0s, w1p, b1, h1s, nullptr, b,
                                               lane, wv);
  __syncthreads();
  // phase 3: conv2 128->256, 125->123 (wave = 8m x 2n)
  conv16<128, 256, 125, 123, 7, 8, 8, 2, false>(h1s, w2p, b2, h2s, nullptr, b,
                                                lane, wv);
  __syncthreads();
  // phase 4: conv3 256->256, 123->121 -> global h3 (wave = 8m x 2n)
  conv16<256, 256, 123, 121, 8, 0, 8, 2, true>(h2s, w3p, b3, nullptr, h3, b,
                                               lane, wv);
}

// ---------------------------------------------------------------- fc1
// LDS-free: block = 208m (mh half of padded 416) x 256n, K-slice.
// grid 256: x=bid&7 (XCD), nb, panel=(q*8+x) -> slice=panel>>1, mh=panel&1:
// each XCD hosts 4 (slice,mh) A-panels (~4MB) shared by its nb-blocks via L2.
// All 8 waves share the same 13 A-frags per K32 (L1 dedup). No barriers.
__global__ __launch_bounds__(512) void k_fc1(const unsigned short* __restrict__ h3,
                                             const unsigned short* __restrict__ xbf,
                                             const unsigned short* __restrict__ wf1r,
                                             float* __restrict__ fpart, int chunkN,
                                             int S, int NBC) {
  const int tid = threadIdx.x;
  const int lane = tid & 63, wv = tid >> 6, lq = lane >> 4, lr = lane & 15;
  const int x8 = blockIdx.x & 7, r = blockIdx.x >> 3;
  const int nb = r % NBC, q = r / NBC;
  const int panel = q * 8 + x8;
  const int slice = panel >> 1, mh = panel & 1;
  const int bbase = nb * 256;
  const int per = 1224 / S, rem = 1224 - per * S;
  const int c0 = slice * per + (slice < rem ? slice : rem);
  const int c1 = c0 + per + (slice < rem ? 1 : 0);

  f32x4 acc[13][2];
#pragma unroll
  for (int mt = 0; mt < 13; ++mt) {
    acc[mt][0] = (f32x4){0.f, 0.f, 0.f, 0.f};
    acc[mt][1] = (f32x4){0.f, 0.f, 0.f, 0.f};
  }

  size_t arow[13];
#pragma unroll
  for (int mt = 0; mt < 13; ++mt)
    arow[mt] = (size_t)(mh * 208 + mt * 16 + lr) * 39168;

  const int bb0 = bbase + (wv * 2 + 0) * 16 + lr;
  const int bb1 = bbase + (wv * 2 + 1) * 16 + lr;
  const unsigned short* pb0h = h3 + (size_t)bb0 * 30976;
  const unsigned short* pb1h = h3 + (size_t)bb1 * 30976;
  const unsigned short* pb0x = xbf + (size_t)bb0 * 8192;
  const unsigned short* pb1x = xbf + (size_t)bb1 * 8192;

#define FC1_BODY(P0, P1, KOFF)                                               \
  {                                                                          \
    const int k = kk * 32 + lq * 8;                                          \
    bf16x8 av[13];                                                           \
    _Pragma("unroll") for (int mt = 0; mt < 13; ++mt) av[mt] =               \
        *(const bf16x8*)(wf1r + arow[mt] + k);                               \
    bf16x8 bbf0 = *(const bf16x8*)((P0) + (k - (KOFF)));                     \
    bf16x8 bbf1 = *(const bf16x8*)((P1) + (k - (KOFF)));                     \
    _Pragma("unroll") for (int mt = 0; mt < 13; ++mt) {                      \
      acc[mt][0] = mfma16(av[mt], bbf0, acc[mt][0]);                         \
      acc[mt][1] = mfma16(av[mt], bbf1, acc[mt][1]);                         \
    }                                                                        \
  }

  const int hb = c1 < 968 ? c1 : 968;
  for (int kk = c0; kk < hb; ++kk) FC1_BODY(pb0h, pb1h, 0)
  const int xa = c0 > 968 ? c0 : 968;
  for (int kk = xa; kk < c1; ++kk) FC1_BODY(pb0x, pb1x, 30976)
#undef FC1_BODY

#pragma unroll
  for (int mt = 0; mt < 13; ++mt) {
    const int m0 = mh * 208 + mt * 16 + lq * 4;
#pragma unroll
    for (int ni = 0; ni < 2; ++ni) {
      const int bb = bbase + (wv * 2 + ni) * 16 + lr;
      *(f32x4*)(fpart + ((size_t)slice * chunkN + bb) * 416 + m0) = acc[mt][ni];
    }
  }
}

__global__ __launch_bounds__(256) void k_fc1red(const float* __restrict__ fpart,
                                                const float* __restrict__ bf1,
                                                float* __restrict__ fc, int chunkN,
                                                int S) {
  int idx = blockIdx.x * 256 + threadIdx.x;
  if (idx >= chunkN * 400) return;
  int bq = idx / 400, m = idx - bq * 400;
  float s = bf1[m];
  for (int sl = 0; sl < S; ++sl)
    s += fpart[((size_t)sl * chunkN + bq) * 416 + m];
  fc[idx] = relu(s);
}

__global__ __launch_bounds__(256) void k_fc2(const float* __restrict__ fc,
                                             const float* __restrict__ wf2,
                                             const float* __restrict__ bf2,
                                             float* __restrict__ out) {
  int b = blockIdx.x * 4 + (threadIdx.x >> 6);
  int lane = threadIdx.x & 63;
  float s = 0.f;
  for (int m = lane; m < 400; m += 64) s += fc[(size_t)b * 400 + m] * wf2[m];
#pragma unroll
  for (int off = 32; off > 0; off >>= 1) s += __shfl_down(s, off, 64);
  if (lane == 0) out[b] = s + bf2[0];
}

// ---------------------------------------------------------------- launch
extern "C" void kernel_launch(void* const* d_in, const int* in_sizes, int n_in,
                              void* d_out, int out_size, void* d_ws, size_t ws_size,
                              hipStream_t stream) {
  const float* x = (const float*)d_in[0];
  const float* Wp = (const float*)d_in[1];
  const float* bp = (const float*)d_in[2];
  const float* W1 = (const float*)d_in[3];
  const float* b1 = (const float*)d_in[4];
  const float* W2 = (const float*)d_in[5];
  const float* b2 = (const float*)d_in[6];
  const float* W3 = (const float*)d_in[7];
  const float* b3 = (const float*)d_in[8];
  const float* Wf1 = (const float*)d_in[9];
  const float* bf1 = (const float*)d_in[10];
  const float* Wf2 = (const float*)d_in[11];
  const float* bf2 = (const float*)d_in[12];
  float* out = (float*)d_out;

  // choose chunkN: largest that fits ws
  const size_t fixedw = 8192 + 49152 + 196608 + 393216 + 416ULL * 39168 * 2;
  const size_t fpartB = 32768ULL * 416 * 4;  // S*chunkN == 32768 for all configs
  int chunkN = 512;
  {
    const int cands[3] = {2048, 1024, 512};
    for (int i = 0; i < 3; ++i) {
      size_t need = fixedw + fpartB +
                    (size_t)cands[i] * (61952ULL + 16384ULL + 1600ULL);
      if (need <= ws_size) {
        chunkN = cands[i];
        break;
      }
    }
  }
  const int nchunk = NB / chunkN;
  const int NBC = chunkN / 256;
  const int S = 128 / NBC;

  char* ws = (char*)d_ws;
  size_t off = 0;
  unsigned short* h3c = (unsigned short*)(ws + off);
  off += (size_t)chunkN * 61952ULL;
  unsigned short* xbfc = (unsigned short*)(ws + off);
  off += (size_t)chunkN * 16384ULL;
  float* fpart = (float*)(ws + off);
  off += fpartB;
  float* fc = (float*)(ws + off);
  off += (size_t)chunkN * 1600ULL;
  unsigned short* wp1r = (unsigned short*)(ws + off);
  off += 8192;
  unsigned short* w1p = (unsigned short*)(ws + off);
  off += 49152;
  unsigned short* w2p = (unsigned short*)(ws + off);
  off += 196608;
  unsigned short* w3p = (unsigned short*)(ws + off);
  off += 393216;
  unsigned short* wf1r = (unsigned short*)(ws + off);

  k_prep_w<<<1264, 256, 0, stream>>>(Wp, W1, W2, W3, wp1r, w1p, w2p, w3p);
  k_prep_wf1<<<416, 256, 66560, stream>>>(Wf1, wf1r);

  for (int c = 0; c < nchunk; ++c) {
    const float* xc = x + (size_t)c * chunkN * 8192;
    k_front<<<chunkN, 512, 94976, stream>>>(xc, Wp, bp, wp1r, w1p, b1, w2p, b2,
                                            w3p, b3, h3c, xbfc);
    k_fc1<<<256, 512, 0, stream>>>(h3c, xbfc, wf1r, fpart, chunkN, S, NBC);
    k_fc1red<<<(chunkN * 400 + 255) / 256, 256, 0, stream>>>(fpart, bf1, fc,
                                                             chunkN, S);
    k_fc2<<<chunkN / 4, 256, 0, stream>>>(fc, Wf2, bf2, out + (size_t)c * chunkN);
  }
}